// Round 3
// baseline (1207.247 us; speedup 1.0000x reference)
//
#include <hip/hip_runtime.h>

typedef __bf16 bf16x8 __attribute__((ext_vector_type(8)));
typedef float f32x4 __attribute__((ext_vector_type(4)));
typedef unsigned int u32x4 __attribute__((ext_vector_type(4)));

#define S_LEN 256
#define BATCH 64
#define HID   1024
#define NWG   256
#define SBH   (S_LEN * BATCH * HID)   /* 16777216 */
#define BH    (BATCH * HID)           /* 65536 */
/* bar layout (ints): slots[4][64] at 0. Monotone per-WG step counters, no reset. */
#define BAR_INTS 256

__device__ __forceinline__ float sigm(float v) { return 1.0f / (1.0f + __expf(-v)); }
__device__ __forceinline__ float tanh_fast(float v) {
  float e = __expf(-2.0f * __builtin_fabsf(v));
  float r = (1.0f - e) / (1.0f + e);
  return __builtin_copysignf(r, v);
}

// Pack 8 f32 -> 8 bf16 (RNE via compiler cvt) into one 16B word.
__device__ __forceinline__ u32x4 cvt8(float4 a, float4 b) {
  union { unsigned short us[8]; u32x4 v; } r;
  r.us[0] = __builtin_bit_cast(unsigned short, (__bf16)a.x);
  r.us[1] = __builtin_bit_cast(unsigned short, (__bf16)a.y);
  r.us[2] = __builtin_bit_cast(unsigned short, (__bf16)a.z);
  r.us[3] = __builtin_bit_cast(unsigned short, (__bf16)a.w);
  r.us[4] = __builtin_bit_cast(unsigned short, (__bf16)b.x);
  r.us[5] = __builtin_bit_cast(unsigned short, (__bf16)b.y);
  r.us[6] = __builtin_bit_cast(unsigned short, (__bf16)b.z);
  r.us[7] = __builtin_bit_cast(unsigned short, (__bf16)b.w);
  return r.v;
}

// 8 x global_load_dwordx4 from base %8 + kc*64B, then vmcnt(0).
// Early-clobber outputs + internal waitcnt => no compiler copy can read in-flight regs.
#define LOAD8_X4(dst, base, MODS)                                             \
  asm volatile(                                                               \
      "global_load_dwordx4 %0, %8, off offset:0 " MODS "\n\t"                 \
      "global_load_dwordx4 %1, %8, off offset:64 " MODS "\n\t"                \
      "global_load_dwordx4 %2, %8, off offset:128 " MODS "\n\t"               \
      "global_load_dwordx4 %3, %8, off offset:192 " MODS "\n\t"               \
      "global_load_dwordx4 %4, %8, off offset:256 " MODS "\n\t"               \
      "global_load_dwordx4 %5, %8, off offset:320 " MODS "\n\t"               \
      "global_load_dwordx4 %6, %8, off offset:384 " MODS "\n\t"               \
      "global_load_dwordx4 %7, %8, off offset:448 " MODS "\n\t"               \
      "s_waitcnt vmcnt(0)"                                                    \
      : "=&v"((dst)[0]), "=&v"((dst)[1]), "=&v"((dst)[2]), "=&v"((dst)[3]),   \
        "=&v"((dst)[4]), "=&v"((dst)[5]), "=&v"((dst)[6]), "=&v"((dst)[7])    \
      : "v"(base)                                                             \
      : "memory")

// Vectorized prep: 8-wide conversions, compile-time weight pointers (no scratch array).
__global__ void prep_kernel(const float* __restrict__ x, const float* __restrict__ h0,
                            const float* __restrict__ Wf, const float* __restrict__ Wi,
                            const float* __restrict__ Wg, const float* __restrict__ Wo,
                            __bf16* __restrict__ x_bf, __bf16* __restrict__ w_x,
                            __bf16* __restrict__ w_h, __bf16* __restrict__ h_buf,
                            int* __restrict__ bar) {
  size_t tid = (size_t)blockIdx.x * blockDim.x + threadIdx.x;
  size_t stride = (size_t)gridDim.x * blockDim.x;     // 524288 threads

  // x: f32 -> bf16, 8 elems/iter
  for (size_t i = tid; i < (size_t)(SBH / 8); i += stride) {
    const float4* s = (const float4*)x + i * 2;
    ((u32x4*)x_bf)[i] = cvt8(s[0], s[1]);
  }

  // weights: compile-time matrix pointer per loop (runtime-indexed ptr array -> scratch).
#define W_CONV(W, gidx)                                                        \
  for (size_t i = tid; i < (size_t)(1024 * 128); i += stride) {                \
    int j   = (int)(i >> 7);                                                   \
    int kc8 = (int)(i & 127);                                                  \
    const float* row = (W) + (size_t)j * 2048;                                 \
    const float4* sx = (const float4*)(row + kc8 * 8);                         \
    const float4* sh = (const float4*)(row + 1024 + kc8 * 8);                  \
    size_t dst = (size_t)((gidx) * 1024 + j) * 128 + kc8;                      \
    ((u32x4*)w_x)[dst] = cvt8(sx[0], sx[1]);                                   \
    ((u32x4*)w_h)[dst] = cvt8(sh[0], sh[1]);                                   \
  }
  W_CONV(Wf, 0)
  W_CONV(Wi, 1)
  W_CONV(Wg, 2)
  W_CONV(Wo, 3)
#undef W_CONV

  // h0 -> bf16 (first h_buf half only; t=0 reads roff=0)
  for (size_t i = tid; i < (size_t)(BH / 8); i += stride) {
    const float4* s = (const float4*)h0 + i * 2;
    ((u32x4*)h_buf)[i] = cvt8(s[0], s[1]);
  }

  for (size_t i = tid; i < BAR_INTS; i += stride) bar[i] = 0;
}

// 256 WGs x 256 thr (1 WG/CU). WG: M=16 batches x N=64 gate-cols (16 units x 4 gates).
// v3 K-split: ALL FOUR waves own a K-quarter (256) of BOTH Wh and Wx.
//   - h-side (critical path, after barrier): 8 loads + 4 chains x 8 MFMA per wave.
//   - x-side: computed for step t+1 DURING the poll window (needs no sync) and
//     carried in acc_x registers across the barrier. Fully off critical path.
// Publication (v3): h packed via LDS, published as 32 x global_store_dwordx4
// sc0 sc1 by wave 0 lanes 0-31; only wave 0's vmcnt gates the slot store
// (no full-WG drain barrier). Wave 1 polls LATE (after its window work) with
// one coalesced 256B load + ballot. Zero RMWs anywhere.
__global__ __launch_bounds__(256, 1) void lstm_kernel(
    const float* __restrict__ x, const float* __restrict__ c0,
    const float* __restrict__ bfp, const float* __restrict__ bip,
    const float* __restrict__ bgp, const float* __restrict__ bop,
    const __bf16* __restrict__ x_bf, const __bf16* __restrict__ w_x,
    const __bf16* __restrict__ w_h, __bf16* __restrict__ h_buf,
    int* __restrict__ bar, float* __restrict__ out) {
  const int tid    = threadIdx.x;
  const int wgid   = blockIdx.x;
  const int m_idx  = wgid & 3;           // batch-tile group (independent chains)
  const int m_base = m_idx * 16;         // batch tile: 0/16/32/48
  const int U      = (wgid >> 2) * 16;   // 16 hidden units per WG
  const int wave   = tid >> 6;           // K-quarter owner (k in [256*wave, 256*wave+256))
  const int lane   = tid & 63;
  const int l16    = lane & 15;
  const int kq8    = (lane >> 4) * 8;
  const int kbase  = wave * 256;
  const int wg_in_grp = wgid >> 2;       // 0..63 within group

  int* slots = bar + m_idx * 64;         // this group's 64 slot words (256 B)

  __shared__ float zbuf[4][16][65];      // per-wave partial z tiles (padded stride 65)
  __shared__ __bf16 hpack[16][16];       // packed h tile for wide publication

  // ---- Resident B: 64 frags. [0..31] = Wh (4 gates x 8 kc), [32..63] = Wx ----
  u32x4 Braw[64];
#pragma unroll
  for (int n = 0; n < 4; ++n) {
    unsigned long gbh =
        (unsigned long)(w_h + (size_t)(n * 1024 + U + l16) * HID + kbase + kq8);
    LOAD8_X4(&Braw[n * 8], gbh, "");
  }
#pragma unroll
  for (int n = 0; n < 4; ++n) {
    unsigned long gbx =
        (unsigned long)(w_x + (size_t)(n * 1024 + U + l16) * HID + kbase + kq8);
    LOAD8_X4(&Braw[32 + n * 8], gbx, "");
  }

  // ---- Per-thread state: (b_loc = tid>>4, u_loc = tid&15) ----
  const int b_loc  = tid >> 4;
  const int u_loc  = tid & 15;
  const int j_t    = U + u_loc;
  const int b_glob = m_base + b_loc;
  float c = c0[(size_t)b_glob * HID + j_t];
  const float bias_f = bfp[j_t], bias_i = bip[j_t], bias_g = bgp[j_t], bias_o = bop[j_t];

  // ---- Prologue: x(0) partials now; x(1) frags staged for the first window ----
  u32x4 Araw_x[8];
  {
    const __bf16* xp = x_bf + (size_t)(m_base + l16) * HID + kbase + kq8;
#pragma unroll
    for (int kc = 0; kc < 8; ++kc) Araw_x[kc] = *(const u32x4*)(xp + kc * 32);
  }
  f32x4 accx0 = {0,0,0,0}, accx1 = {0,0,0,0}, accx2 = {0,0,0,0}, accx3 = {0,0,0,0};
#pragma unroll
  for (int kc = 0; kc < 8; ++kc) {
    bf16x8 a = __builtin_bit_cast(bf16x8, Araw_x[kc]);
    accx0 = __builtin_amdgcn_mfma_f32_16x16x32_bf16(a, __builtin_bit_cast(bf16x8, Braw[32 +  0 + kc]), accx0, 0, 0, 0);
    accx1 = __builtin_amdgcn_mfma_f32_16x16x32_bf16(a, __builtin_bit_cast(bf16x8, Braw[32 +  8 + kc]), accx1, 0, 0, 0);
    accx2 = __builtin_amdgcn_mfma_f32_16x16x32_bf16(a, __builtin_bit_cast(bf16x8, Braw[32 + 16 + kc]), accx2, 0, 0, 0);
    accx3 = __builtin_amdgcn_mfma_f32_16x16x32_bf16(a, __builtin_bit_cast(bf16x8, Braw[32 + 24 + kc]), accx3, 0, 0, 0);
  }
  {
    const __bf16* xp = x_bf + (size_t)(BATCH + m_base + l16) * HID + kbase + kq8;
#pragma unroll
    for (int kc = 0; kc < 8; ++kc) Araw_x[kc] = *(const u32x4*)(xp + kc * 32);
  }

  for (int t = 0; t < S_LEN; ++t) {
    const size_t roff = (t & 1) ? (size_t)BH : 0;
    const size_t woff = (t & 1) ? 0 : (size_t)BH;

    // ---- h frags (K=256 slice) straight to registers; LLC-coherent loads ----
    u32x4 Araw_h[8];
    {
      unsigned long ga = (unsigned long)(h_buf + roff + (size_t)(m_base + l16) * HID +
                                         kbase + kq8);
      LOAD8_X4(Araw_h, ga, "sc0 sc1");
    }

    // ---- h-side MFMA: 4 chains x 8, accumulating onto the x partials ----
    f32x4 acc0 = accx0, acc1 = accx1, acc2 = accx2, acc3 = accx3;
#pragma unroll
    for (int kc = 0; kc < 8; ++kc) {
      bf16x8 a = __builtin_bit_cast(bf16x8, Araw_h[kc]);
      acc0 = __builtin_amdgcn_mfma_f32_16x16x32_bf16(a, __builtin_bit_cast(bf16x8, Braw[ 0 + kc]), acc0, 0, 0, 0);
      acc1 = __builtin_amdgcn_mfma_f32_16x16x32_bf16(a, __builtin_bit_cast(bf16x8, Braw[ 8 + kc]), acc1, 0, 0, 0);
      acc2 = __builtin_amdgcn_mfma_f32_16x16x32_bf16(a, __builtin_bit_cast(bf16x8, Braw[16 + kc]), acc2, 0, 0, 0);
      acc3 = __builtin_amdgcn_mfma_f32_16x16x32_bf16(a, __builtin_bit_cast(bf16x8, Braw[24 + kc]), acc3, 0, 0, 0);
    }

    // ---- z partials to LDS: C/D row = quad*4+r (batch-local), col = gate*16 + l16 ----
    {
      int q = lane >> 4;
#pragma unroll
      for (int r = 0; r < 4; ++r) {
        zbuf[wave][q * 4 + r][ 0 + l16] = acc0[r];
        zbuf[wave][q * 4 + r][16 + l16] = acc1[r];
        zbuf[wave][q * 4 + r][32 + l16] = acc2[r];
        zbuf[wave][q * 4 + r][48 + l16] = acc3[r];
      }
    }
    __syncthreads();

    // ---- Combine gates, update c, h ----
    float h;
    {
      float zf = 0.f, zi = 0.f, zg = 0.f, zo = 0.f;
#pragma unroll
      for (int w = 0; w < 4; ++w) {
        zf += zbuf[w][b_loc][ 0 + u_loc];
        zi += zbuf[w][b_loc][16 + u_loc];
        zg += zbuf[w][b_loc][32 + u_loc];
        zo += zbuf[w][b_loc][48 + u_loc];
      }
      float fg = sigm(zf + bias_f);
      float ig = sigm(zi + bias_i);
      float gg = tanh_fast(zg + bias_g);
      float og = sigm(zo + bias_o);
      c = fg * c + ig * gg;
      h = og * tanh_fast(c);
    }

    if (t < S_LEN - 1) {
      hpack[b_loc][u_loc] = (__bf16)h;
      __syncthreads();   // hpack complete (LDS only — no global drain semantics)

      // ---- Wave 0 lanes 0-31: publish 512B as 32 x dwordx4 sc0 sc1; slot after ack ----
      if (tid < 32) {
        int b = tid >> 1, hf = tid & 1;
        u32x4 hv = *(const u32x4*)(&hpack[b][hf * 8]);
        unsigned long ha = (unsigned long)(h_buf + woff +
                                           (size_t)(m_base + b) * HID + U + hf * 8);
        asm volatile("global_store_dwordx4 %0, %1, off sc0 sc1\n\t"
                     "s_waitcnt vmcnt(0)"
                     :: "v"(ha), "v"(hv) : "memory");
      }
      if (tid == 0) {
        __hip_atomic_store(&slots[wg_in_grp], t + 1,
                           __ATOMIC_RELAXED, __HIP_MEMORY_SCOPE_AGENT);
      }

      // ---- Overlapped with other WGs' publishes: out-write + x window ----
      {
        size_t oi = ((size_t)(t * BATCH + b_glob)) * HID + j_t;
        out[oi] = x[oi] + h;
      }
      // x-side partials for step t+1 (Araw_x holds x(t+1)); then stage x(t+2)
      accx0 = (f32x4){0,0,0,0}; accx1 = (f32x4){0,0,0,0};
      accx2 = (f32x4){0,0,0,0}; accx3 = (f32x4){0,0,0,0};
#pragma unroll
      for (int kc = 0; kc < 8; ++kc) {
        bf16x8 a = __builtin_bit_cast(bf16x8, Araw_x[kc]);
        accx0 = __builtin_amdgcn_mfma_f32_16x16x32_bf16(a, __builtin_bit_cast(bf16x8, Braw[32 +  0 + kc]), accx0, 0, 0, 0);
        accx1 = __builtin_amdgcn_mfma_f32_16x16x32_bf16(a, __builtin_bit_cast(bf16x8, Braw[32 +  8 + kc]), accx1, 0, 0, 0);
        accx2 = __builtin_amdgcn_mfma_f32_16x16x32_bf16(a, __builtin_bit_cast(bf16x8, Braw[32 + 16 + kc]), accx2, 0, 0, 0);
        accx3 = __builtin_amdgcn_mfma_f32_16x16x32_bf16(a, __builtin_bit_cast(bf16x8, Braw[32 + 24 + kc]), accx3, 0, 0, 0);
      }
      {
        int tn = (t + 2 < S_LEN) ? (t + 2) : (S_LEN - 1);
        const __bf16* xp =
            x_bf + ((size_t)(tn * BATCH + m_base + l16)) * HID + kbase + kq8;
#pragma unroll
        for (int kc = 0; kc < 8; ++kc) Araw_x[kc] = *(const u32x4*)(xp + kc * 32);
      }

      // ---- Wave 1: late poll (one coalesced 256B load + ballot) ----
      if (wave == 1) {
        const int target = t + 1;
        while (true) {
          int v = __hip_atomic_load(&slots[lane],
                                    __ATOMIC_RELAXED, __HIP_MEMORY_SCOPE_AGENT);
          if (__ballot(v >= target) == ~0ull) break;
          __builtin_amdgcn_s_sleep(1);
        }
      }
      __syncthreads();
    } else {
      size_t oi = ((size_t)(t * BATCH + b_glob)) * HID + j_t;
      out[oi] = x[oi] + h;
      out[(size_t)SBH + (size_t)b_glob * HID + j_t] = h;         // h_f
      out[(size_t)SBH + BH + (size_t)b_glob * HID + j_t] = c;    // c_f
    }
  }
}

extern "C" void kernel_launch(void* const* d_in, const int* in_sizes, int n_in,
                              void* d_out, int out_size, void* d_ws, size_t ws_size,
                              hipStream_t stream) {
  const float* x   = (const float*)d_in[0];
  const float* h0  = (const float*)d_in[1];
  const float* c0  = (const float*)d_in[2];
  const float* Wf  = (const float*)d_in[3];
  const float* bf_ = (const float*)d_in[4];
  const float* Wi  = (const float*)d_in[5];
  const float* bi_ = (const float*)d_in[6];
  const float* Wg  = (const float*)d_in[7];
  const float* bg_ = (const float*)d_in[8];
  const float* Wo  = (const float*)d_in[9];
  const float* bo_ = (const float*)d_in[10];

  char* ws = (char*)d_ws;
  size_t off = 0;
  __bf16* x_bf = (__bf16*)(ws + off); off += (size_t)SBH * 2;              // 32 MB
  __bf16* w_x  = (__bf16*)(ws + off); off += (size_t)4 * 1024 * 1024 * 2;  // 8 MB
  __bf16* w_h  = (__bf16*)(ws + off); off += (size_t)4 * 1024 * 1024 * 2;  // 8 MB
  __bf16* h_buf = (__bf16*)(ws + off); off += (size_t)2 * BH * 2;          // 256 KB
  int* bar = (int*)(ws + off); off += BAR_INTS * sizeof(int);
  if (ws_size < off) return;

  float* out = (float*)d_out;

  prep_kernel<<<2048, 256, 0, stream>>>(x, h0, Wf, Wi, Wg, Wo, x_bf, w_x, w_h, h_buf, bar);
  lstm_kernel<<<NWG, 256, 0, stream>>>(x, c0, bf_, bi_, bg_, bo_, x_bf, w_x, w_h, h_buf, bar, out);
}

// Round 4
// 1071.043 us; speedup vs baseline: 1.1272x; 1.1272x over previous
//
#include <hip/hip_runtime.h>

typedef __bf16 bf16x8 __attribute__((ext_vector_type(8)));
typedef float f32x4 __attribute__((ext_vector_type(4)));
typedef unsigned int u32x4 __attribute__((ext_vector_type(4)));

#define S_LEN 256
#define BATCH 64
#define HID   1024
#define NWG   256
#define SBH   (S_LEN * BATCH * HID)   /* 16777216 */
#define BH    (BATCH * HID)           /* 65536 */

__device__ __forceinline__ float sigm(float v) { return 1.0f / (1.0f + __expf(-v)); }
__device__ __forceinline__ float tanh_fast(float v) {
  float e = __expf(-2.0f * __builtin_fabsf(v));
  float r = (1.0f - e) / (1.0f + e);
  return __builtin_copysignf(r, v);
}

// Pack 8 f32 -> 8 bf16 (RNE via compiler cvt) into one 16B word.
__device__ __forceinline__ u32x4 cvt8(float4 a, float4 b) {
  union { unsigned short us[8]; u32x4 v; } r;
  r.us[0] = __builtin_bit_cast(unsigned short, (__bf16)a.x);
  r.us[1] = __builtin_bit_cast(unsigned short, (__bf16)a.y);
  r.us[2] = __builtin_bit_cast(unsigned short, (__bf16)a.z);
  r.us[3] = __builtin_bit_cast(unsigned short, (__bf16)a.w);
  r.us[4] = __builtin_bit_cast(unsigned short, (__bf16)b.x);
  r.us[5] = __builtin_bit_cast(unsigned short, (__bf16)b.y);
  r.us[6] = __builtin_bit_cast(unsigned short, (__bf16)b.z);
  r.us[7] = __builtin_bit_cast(unsigned short, (__bf16)b.w);
  return r.v;
}

// 8 x global_load_dwordx4 from base %8 + kc*64B, then vmcnt(0).
// Early-clobber outputs + internal waitcnt => no compiler copy can read in-flight regs.
#define LOAD8_X4(dst, base, MODS)                                             \
  asm volatile(                                                               \
      "global_load_dwordx4 %0, %8, off offset:0 " MODS "\n\t"                 \
      "global_load_dwordx4 %1, %8, off offset:64 " MODS "\n\t"                \
      "global_load_dwordx4 %2, %8, off offset:128 " MODS "\n\t"               \
      "global_load_dwordx4 %3, %8, off offset:192 " MODS "\n\t"               \
      "global_load_dwordx4 %4, %8, off offset:256 " MODS "\n\t"               \
      "global_load_dwordx4 %5, %8, off offset:320 " MODS "\n\t"               \
      "global_load_dwordx4 %6, %8, off offset:384 " MODS "\n\t"               \
      "global_load_dwordx4 %7, %8, off offset:448 " MODS "\n\t"               \
      "s_waitcnt vmcnt(0)"                                                    \
      : "=&v"((dst)[0]), "=&v"((dst)[1]), "=&v"((dst)[2]), "=&v"((dst)[3]),   \
        "=&v"((dst)[4]), "=&v"((dst)[5]), "=&v"((dst)[6]), "=&v"((dst)[7])    \
      : "v"(base)                                                             \
      : "memory")

// Vectorized prep. h_buf region 0 = h0 with bit0 cleared (epoch marker 0);
// region 1 poisoned with bit0=1 (differs from first producer marker 0).
__global__ void prep_kernel(const float* __restrict__ x, const float* __restrict__ h0,
                            const float* __restrict__ Wf, const float* __restrict__ Wi,
                            const float* __restrict__ Wg, const float* __restrict__ Wo,
                            __bf16* __restrict__ x_bf, __bf16* __restrict__ w_x,
                            __bf16* __restrict__ w_h, __bf16* __restrict__ h_buf) {
  size_t tid = (size_t)blockIdx.x * blockDim.x + threadIdx.x;
  size_t stride = (size_t)gridDim.x * blockDim.x;     // 524288 threads

  // x: f32 -> bf16, 8 elems/iter
  for (size_t i = tid; i < (size_t)(SBH / 8); i += stride) {
    const float4* s = (const float4*)x + i * 2;
    ((u32x4*)x_bf)[i] = cvt8(s[0], s[1]);
  }

  // weights: compile-time matrix pointer per loop (runtime-indexed ptr array -> scratch).
#define W_CONV(W, gidx)                                                        \
  for (size_t i = tid; i < (size_t)(1024 * 128); i += stride) {                \
    int j   = (int)(i >> 7);                                                   \
    int kc8 = (int)(i & 127);                                                  \
    const float* row = (W) + (size_t)j * 2048;                                 \
    const float4* sx = (const float4*)(row + kc8 * 8);                         \
    const float4* sh = (const float4*)(row + 1024 + kc8 * 8);                  \
    size_t dst = (size_t)((gidx) * 1024 + j) * 128 + kc8;                      \
    ((u32x4*)w_x)[dst] = cvt8(sx[0], sx[1]);                                   \
    ((u32x4*)w_h)[dst] = cvt8(sh[0], sh[1]);                                   \
  }
  W_CONV(Wf, 0)
  W_CONV(Wi, 1)
  W_CONV(Wg, 2)
  W_CONV(Wo, 3)
#undef W_CONV

  // h0 -> bf16, low mantissa bit forced to 0 (epoch marker for consume-step 0)
  for (size_t i = tid; i < (size_t)(BH / 8); i += stride) {
    const float4* s = (const float4*)h0 + i * 2;
    u32x4 v = cvt8(s[0], s[1]);
    v &= 0xFFFEFFFEu;
    ((u32x4*)h_buf)[i] = v;
  }

  // region 1 poison: bit0=1 everywhere (stale vs first producer marker 0)
  for (size_t i = tid; i < (size_t)(BH / 8); i += stride) {
    u32x4 p = {0x00010001u, 0x00010001u, 0x00010001u, 0x00010001u};
    ((u32x4*)(h_buf + BH))[i] = p;
  }
}

// 256 WGs x 256 thr (1 WG/CU). WG: M=16 batches x N=64 gate-cols (16 units x 4 gates).
// All four waves own a K-quarter (256) of BOTH Wh and Wx (x-side done in the
// post-publish window, h-side on the critical path).
//
// v4 sync: NO flags, NO inter-WG barrier. h is published bf16 with its low
// mantissa bit forced to an epoch marker; consumers poll-load their h K-slice
// and accept when EVERY value's marker matches the expected epoch (monotone
// freshness => retry terminates; per-value check => torn visibility safe).
// Chain per step = store one-way + load RT, no ack, no flag hops. WGs drift
// with depth-1 slack instead of hard-barriering every step.
// Marker schedule: consumer at step t expects (t>>1)&1; producer at step t
// writes ((t+1)>>1)&1. Double-buffered regions alternate markers each reuse.
__global__ __launch_bounds__(256, 1) void lstm_kernel(
    const float* __restrict__ x, const float* __restrict__ c0,
    const float* __restrict__ bfp, const float* __restrict__ bip,
    const float* __restrict__ bgp, const float* __restrict__ bop,
    const __bf16* __restrict__ x_bf, const __bf16* __restrict__ w_x,
    const __bf16* __restrict__ w_h, __bf16* __restrict__ h_buf,
    float* __restrict__ out) {
  const int tid    = threadIdx.x;
  const int wgid   = blockIdx.x;
  const int m_idx  = wgid & 3;           // batch-tile group
  const int m_base = m_idx * 16;         // batch tile: 0/16/32/48
  const int U      = (wgid >> 2) * 16;   // 16 hidden units per WG
  const int wave   = tid >> 6;           // K-quarter owner (k in [256*wave, ...))
  const int lane   = tid & 63;
  const int l16    = lane & 15;
  const int kq8    = (lane >> 4) * 8;
  const int kbase  = wave * 256;

  __shared__ float zbuf[2][4][16][65];       // parity double-buffered partials
  __shared__ unsigned short hpack[16][16];   // per-wave publication staging

  // ---- Resident B: 64 frags. [0..31] = Wh (4 gates x 8 kc), [32..63] = Wx ----
  u32x4 Braw[64];
#pragma unroll
  for (int n = 0; n < 4; ++n) {
    unsigned long gbh =
        (unsigned long)(w_h + (size_t)(n * 1024 + U + l16) * HID + kbase + kq8);
    LOAD8_X4(&Braw[n * 8], gbh, "");
  }
#pragma unroll
  for (int n = 0; n < 4; ++n) {
    unsigned long gbx =
        (unsigned long)(w_x + (size_t)(n * 1024 + U + l16) * HID + kbase + kq8);
    LOAD8_X4(&Braw[32 + n * 8], gbx, "");
  }

  // ---- Per-thread state: (b_loc = tid>>4, u_loc = tid&15) ----
  const int b_loc  = tid >> 4;
  const int u_loc  = tid & 15;
  const int j_t    = U + u_loc;
  const int b_glob = m_base + b_loc;
  float c = c0[(size_t)b_glob * HID + j_t];
  const float bias_f = bfp[j_t], bias_i = bip[j_t], bias_g = bgp[j_t], bias_o = bop[j_t];

  // ---- Prologue: x(0) partials now; x(1) frags staged for the first window ----
  u32x4 Araw_x[8];
  {
    const __bf16* xp = x_bf + (size_t)(m_base + l16) * HID + kbase + kq8;
#pragma unroll
    for (int kc = 0; kc < 8; ++kc) Araw_x[kc] = *(const u32x4*)(xp + kc * 32);
  }
  f32x4 accx0 = {0,0,0,0}, accx1 = {0,0,0,0}, accx2 = {0,0,0,0}, accx3 = {0,0,0,0};
#pragma unroll
  for (int kc = 0; kc < 8; ++kc) {
    bf16x8 a = __builtin_bit_cast(bf16x8, Araw_x[kc]);
    accx0 = __builtin_amdgcn_mfma_f32_16x16x32_bf16(a, __builtin_bit_cast(bf16x8, Braw[32 +  0 + kc]), accx0, 0, 0, 0);
    accx1 = __builtin_amdgcn_mfma_f32_16x16x32_bf16(a, __builtin_bit_cast(bf16x8, Braw[32 +  8 + kc]), accx1, 0, 0, 0);
    accx2 = __builtin_amdgcn_mfma_f32_16x16x32_bf16(a, __builtin_bit_cast(bf16x8, Braw[32 + 16 + kc]), accx2, 0, 0, 0);
    accx3 = __builtin_amdgcn_mfma_f32_16x16x32_bf16(a, __builtin_bit_cast(bf16x8, Braw[32 + 24 + kc]), accx3, 0, 0, 0);
  }
  {
    const __bf16* xp = x_bf + (size_t)(BATCH + m_base + l16) * HID + kbase + kq8;
#pragma unroll
    for (int kc = 0; kc < 8; ++kc) Araw_x[kc] = *(const u32x4*)(xp + kc * 32);
  }

  for (int t = 0; t < S_LEN; ++t) {
    const size_t roff = (t & 1) ? (size_t)BH : 0;
    const size_t woff = (t & 1) ? 0 : (size_t)BH;
    const int zp = t & 1;

    // ---- h K-slice: poll-load until every value carries the expected marker ----
    u32x4 Araw_h[8];
    {
      unsigned long ga = (unsigned long)(h_buf + roff + (size_t)(m_base + l16) * HID +
                                         kbase + kq8);
      const unsigned mexp = ((unsigned)(t >> 1) & 1u) * 0x00010001u;
      LOAD8_X4(Araw_h, ga, "sc0 sc1");
      while (true) {
        unsigned bad = 0;
#pragma unroll
        for (int kc = 0; kc < 8; ++kc) {
          u32x4 w = Araw_h[kc];
          bad |= ((w[0] ^ mexp) & 0x00010001u);
          bad |= ((w[1] ^ mexp) & 0x00010001u);
          bad |= ((w[2] ^ mexp) & 0x00010001u);
          bad |= ((w[3] ^ mexp) & 0x00010001u);
        }
        if (__ballot(bad != 0) == 0ull) break;   // all 64 lanes fully fresh
        __builtin_amdgcn_s_sleep(2);
        LOAD8_X4(Araw_h, ga, "sc0 sc1");
      }
    }

    // ---- h-side MFMA: 4 chains x 8, accumulating onto the x partials ----
    f32x4 acc0 = accx0, acc1 = accx1, acc2 = accx2, acc3 = accx3;
#pragma unroll
    for (int kc = 0; kc < 8; ++kc) {
      bf16x8 a = __builtin_bit_cast(bf16x8, Araw_h[kc]);
      acc0 = __builtin_amdgcn_mfma_f32_16x16x32_bf16(a, __builtin_bit_cast(bf16x8, Braw[ 0 + kc]), acc0, 0, 0, 0);
      acc1 = __builtin_amdgcn_mfma_f32_16x16x32_bf16(a, __builtin_bit_cast(bf16x8, Braw[ 8 + kc]), acc1, 0, 0, 0);
      acc2 = __builtin_amdgcn_mfma_f32_16x16x32_bf16(a, __builtin_bit_cast(bf16x8, Braw[16 + kc]), acc2, 0, 0, 0);
      acc3 = __builtin_amdgcn_mfma_f32_16x16x32_bf16(a, __builtin_bit_cast(bf16x8, Braw[24 + kc]), acc3, 0, 0, 0);
    }

    // ---- z partials to LDS (parity buffer) ----
    {
      int q = lane >> 4;
#pragma unroll
      for (int r = 0; r < 4; ++r) {
        zbuf[zp][wave][q * 4 + r][ 0 + l16] = acc0[r];
        zbuf[zp][wave][q * 4 + r][16 + l16] = acc1[r];
        zbuf[zp][wave][q * 4 + r][32 + l16] = acc2[r];
        zbuf[zp][wave][q * 4 + r][48 + l16] = acc3[r];
      }
    }
    __syncthreads();   // the ONLY barrier per step (intra-WG)

    // ---- Combine gates, update c, h ----
    float h;
    {
      float zf = 0.f, zi = 0.f, zg = 0.f, zo = 0.f;
#pragma unroll
      for (int w = 0; w < 4; ++w) {
        zf += zbuf[zp][w][b_loc][ 0 + u_loc];
        zi += zbuf[zp][w][b_loc][16 + u_loc];
        zg += zbuf[zp][w][b_loc][32 + u_loc];
        zo += zbuf[zp][w][b_loc][48 + u_loc];
      }
      float fg = sigm(zf + bias_f);
      float ig = sigm(zi + bias_i);
      float gg = tanh_fast(zg + bias_g);
      float og = sigm(zo + bias_o);
      c = fg * c + ig * gg;
      h = og * tanh_fast(c);
    }

    if (t < S_LEN - 1) {
      // ---- Publish h with epoch marker; fire-and-forget, per-wave independent ----
      {
        unsigned short hb = __builtin_bit_cast(unsigned short, (__bf16)h);
        hb = (unsigned short)((hb & 0xFFFEu) | (unsigned)(((t + 1) >> 1) & 1));
        hpack[b_loc][u_loc] = hb;
      }
      asm volatile("s_waitcnt lgkmcnt(0)" ::: "memory");
      __builtin_amdgcn_sched_barrier(0);
      if (lane < 8) {
        int b = 4 * wave + (lane >> 1), half = lane & 1;
        u32x4 hv = *(const u32x4*)(&hpack[b][half * 8]);
        unsigned long ha = (unsigned long)(h_buf + woff +
                                           (size_t)(m_base + b) * HID + U + half * 8);
        asm volatile("global_store_dwordx4 %0, %1, off sc0 sc1"
                     :: "v"(ha), "v"(hv) : "memory");
      }

      // ---- Window work (overlaps other WGs' publishes): out + x-side ----
      {
        size_t oi = ((size_t)(t * BATCH + b_glob)) * HID + j_t;
        out[oi] = x[oi] + h;
      }
      accx0 = (f32x4){0,0,0,0}; accx1 = (f32x4){0,0,0,0};
      accx2 = (f32x4){0,0,0,0}; accx3 = (f32x4){0,0,0,0};
#pragma unroll
      for (int kc = 0; kc < 8; ++kc) {
        bf16x8 a = __builtin_bit_cast(bf16x8, Araw_x[kc]);
        accx0 = __builtin_amdgcn_mfma_f32_16x16x32_bf16(a, __builtin_bit_cast(bf16x8, Braw[32 +  0 + kc]), accx0, 0, 0, 0);
        accx1 = __builtin_amdgcn_mfma_f32_16x16x32_bf16(a, __builtin_bit_cast(bf16x8, Braw[32 +  8 + kc]), accx1, 0, 0, 0);
        accx2 = __builtin_amdgcn_mfma_f32_16x16x32_bf16(a, __builtin_bit_cast(bf16x8, Braw[32 + 16 + kc]), accx2, 0, 0, 0);
        accx3 = __builtin_amdgcn_mfma_f32_16x16x32_bf16(a, __builtin_bit_cast(bf16x8, Braw[32 + 24 + kc]), accx3, 0, 0, 0);
      }
      {
        int tn = (t + 2 < S_LEN) ? (t + 2) : (S_LEN - 1);
        const __bf16* xp =
            x_bf + ((size_t)(tn * BATCH + m_base + l16)) * HID + kbase + kq8;
#pragma unroll
        for (int kc = 0; kc < 8; ++kc) Araw_x[kc] = *(const u32x4*)(xp + kc * 32);
      }
    } else {
      size_t oi = ((size_t)(t * BATCH + b_glob)) * HID + j_t;
      out[oi] = x[oi] + h;
      out[(size_t)SBH + (size_t)b_glob * HID + j_t] = h;         // h_f
      out[(size_t)SBH + BH + (size_t)b_glob * HID + j_t] = c;    // c_f
    }
  }
}

extern "C" void kernel_launch(void* const* d_in, const int* in_sizes, int n_in,
                              void* d_out, int out_size, void* d_ws, size_t ws_size,
                              hipStream_t stream) {
  const float* x   = (const float*)d_in[0];
  const float* h0  = (const float*)d_in[1];
  const float* c0  = (const float*)d_in[2];
  const float* Wf  = (const float*)d_in[3];
  const float* bf_ = (const float*)d_in[4];
  const float* Wi  = (const float*)d_in[5];
  const float* bi_ = (const float*)d_in[6];
  const float* Wg  = (const float*)d_in[7];
  const float* bg_ = (const float*)d_in[8];
  const float* Wo  = (const float*)d_in[9];
  const float* bo_ = (const float*)d_in[10];

  char* ws = (char*)d_ws;
  size_t off = 0;
  __bf16* x_bf = (__bf16*)(ws + off); off += (size_t)SBH * 2;              // 32 MB
  __bf16* w_x  = (__bf16*)(ws + off); off += (size_t)4 * 1024 * 1024 * 2;  // 8 MB
  __bf16* w_h  = (__bf16*)(ws + off); off += (size_t)4 * 1024 * 1024 * 2;  // 8 MB
  __bf16* h_buf = (__bf16*)(ws + off); off += (size_t)2 * BH * 2;          // 256 KB
  if (ws_size < off) return;

  float* out = (float*)d_out;

  prep_kernel<<<2048, 256, 0, stream>>>(x, h0, Wf, Wi, Wg, Wo, x_bf, w_x, w_h, h_buf);
  lstm_kernel<<<NWG, 256, 0, stream>>>(x, c0, bf_, bi_, bg_, bo_, x_bf, w_x, w_h, h_buf, out);
}